// Round 1
// baseline (14031.406 us; speedup 1.0000x reference)
//
#include <hip/hip_runtime.h>
#include <math.h>

#define D 64
#define CDIM 128
#define NL 5
#define NB 8
#define HID 256
#define ODIM 1472      // D*(3*NB-1)
#define PPD 23
#define PPDP 24        // padded params per dim
#define NTRI 2016
#define BATCH 32768
#define ROWS 16        // batch rows per block in layer kernel
#define TB 512

__device__ __forceinline__ float softplusf(float x) {
    return fmaxf(x, 0.0f) + log1pf(__expf(-fabsf(x)));
}

// ---------------- precompute: A_t = (L@U)^T per layer, and total LU logdet ----
__global__ void lu_prep(const float* __restrict__ lower_e,
                        const float* __restrict__ upper_e,
                        const float* __restrict__ udiag,
                        float* __restrict__ At, float* __restrict__ lu_const) {
    int l = blockIdx.x;
    int t = threadIdx.x; // 256 threads
    __shared__ float Ls[D * D];
    __shared__ float Us[D * D];
    for (int idx = t; idx < D * D; idx += 256) {
        int i = idx >> 6, j = idx & 63;
        float lv;
        if (i == j)      lv = 1.0f;
        else if (i > j)  lv = lower_e[l * NTRI + (i * (i - 1)) / 2 + j];
        else             lv = 0.0f;
        Ls[idx] = lv;
        float uv;
        if (i == j)      uv = softplusf(udiag[l * D + i]) + 0.001f;
        else if (j > i)  uv = upper_e[l * NTRI + i * (D - 1) - (i * (i - 1)) / 2 + (j - i - 1)];
        else             uv = 0.0f;
        Us[idx] = uv;
    }
    __syncthreads();
    for (int idx = t; idx < D * D; idx += 256) {
        int i = idx >> 6, j = idx & 63;
        float acc = 0.0f;
        int km = min(i, j);
        for (int k = 0; k <= km; ++k) acc += Ls[i * D + k] * Us[k * D + j];
        At[(l * D + j) * D + i] = acc;   // transposed store
    }
    if (l == 0 && t == 0) {
        float s = 0.0f;
        for (int ll = 0; ll < NL; ++ll)
            for (int k = 0; k < D; ++k)
                s += __logf(softplusf(udiag[ll * D + k]) + 0.001f);
        lu_const[0] = s;
    }
}

// ---------------- precompute: W3 transposed+padded: W3p[l][d][k][24] ----------
__global__ void w3t_kernel(const float* __restrict__ W3, float* __restrict__ W3p) {
    int idx = blockIdx.x * 256 + threadIdx.x;
    const int total = NL * D * HID * PPDP;
    if (idx >= total) return;
    int p = idx % PPDP;
    int k = (idx / PPDP) % HID;
    int d = (idx / (PPDP * HID)) % D;
    int l = idx / (PPDP * HID * D);
    W3p[idx] = (p < PPD) ? W3[(l * HID + k) * ODIM + d * PPD + p] : 0.0f;
}

// ---------------- init: copy x, zero logdet ----------------------------------
__global__ void init_kernel(const float* __restrict__ inp, float* __restrict__ x,
                            float* __restrict__ logdet) {
    int i = blockIdx.x * 256 + threadIdx.x;
    if (i < BATCH * D) x[i] = inp[i];
    if (i < BATCH) logdet[i] = 0.0f;
}

// ---------------- spline helpers --------------------------------------------
__device__ __forceinline__ void cumbins(const float* pp, float* c) {
    float m = pp[0];
#pragma unroll
    for (int i = 1; i < NB; ++i) m = fmaxf(m, pp[i]);
    float e[NB];
    float s = 0.0f;
#pragma unroll
    for (int i = 0; i < NB; ++i) { e[i] = __expf(pp[i] - m); s += e[i]; }
    float inv = 1.0f / s;
    c[0] = -5.0f;
    float run = 0.0f;
#pragma unroll
    for (int i = 0; i < NB - 1; ++i) {
        run += fmaf(0.992f, e[i] * inv, 0.001f);
        c[i + 1] = fmaf(10.0f, run, -5.0f);
    }
    c[NB] = 5.0f;
}

__device__ __forceinline__ void rqs(float xv, const float* pp, float& yo, float& ldo) {
    const float Bnd = 5.0f;
    float cw[NB + 1], ch[NB + 1], dv[NB + 1];
    cumbins(pp, cw);
    cumbins(pp + NB, ch);
    dv[0] = 1.0f; dv[NB] = 1.0f;
#pragma unroll
    for (int i = 1; i < NB; ++i) dv[i] = 0.001f + softplusf(pp[15 + i]);
    float xc = fminf(fmaxf(xv, -Bnd), Bnd);
    float icw = cw[0], icw1 = cw[1], ich = ch[0], ich1 = ch[1], d0 = dv[0], d1 = dv[1];
#pragma unroll
    for (int kk = 1; kk < NB; ++kk) {
        bool sel = (xc >= cw[kk]);
        icw  = sel ? cw[kk]     : icw;
        icw1 = sel ? cw[kk + 1] : icw1;
        ich  = sel ? ch[kk]     : ich;
        ich1 = sel ? ch[kk + 1] : ich1;
        d0   = sel ? dv[kk]     : d0;
        d1   = sel ? dv[kk + 1] : d1;
    }
    float iw  = icw1 - icw;
    float ih  = ich1 - ich;
    float dlt = ih / iw;
    float th  = (xc - icw) / iw;
    float omt = 1.0f - th;
    float tomt = th * omt;
    float numer = ih * (dlt * th * th + d0 * tomt);
    float den = dlt + (d0 + d1 - 2.0f * dlt) * tomt;
    float outv = ich + numer / den;
    float dnum = dlt * dlt * (d1 * th * th + 2.0f * dlt * tomt + d0 * omt * omt);
    float ld = __logf(dnum) - 2.0f * __logf(den);
    bool inside = (xv >= -Bnd) && (xv <= Bnd);
    yo  = inside ? outv : xv;
    ldo = inside ? ld : 0.0f;
}

// ---------------- fused per-layer kernel -------------------------------------
__global__ __launch_bounds__(TB) void layer_kernel(
    const float* __restrict__ ctx,
    const float* __restrict__ W1, const float* __restrict__ b1,
    const float* __restrict__ W2, const float* __restrict__ b2,
    const float* __restrict__ W3p, const float* __restrict__ b3,
    const float* __restrict__ lu_bias, const float* __restrict__ At,
    float* __restrict__ x, float* __restrict__ logdet, int l) {
    __shared__ float ctx_s[ROWS * CDIM];   // 8 KB
    __shared__ float hh1_s[ROWS * HID];    // 16 KB
    __shared__ float hh2_s[ROWS * HID];    // 16 KB
    __shared__ float y_s[ROWS * D];        // 4 KB
    const int t = threadIdx.x;
    const int rbase = blockIdx.x * ROWS;

    // load context rows
    for (int i = t; i < ROWS * CDIM; i += TB)
        ctx_s[i] = ctx[rbase * CDIM + i];
    __syncthreads();

    // ---- GEMM1: hh1 = relu(ctx @ W1 + b1), K=128 ----
    {
        const int o = t & 255, rr = t >> 8;   // rr in {0,1}: rows rr*8..rr*8+7
        const float* w1p = W1 + l * CDIM * HID + o;
        float acc[8];
        const float bias = b1[l * HID + o];
#pragma unroll
        for (int r = 0; r < 8; ++r) acc[r] = bias;
        for (int k = 0; k < CDIM; k += 4) {
            float w0 = w1p[(k + 0) * HID];
            float w1v = w1p[(k + 1) * HID];
            float w2v = w1p[(k + 2) * HID];
            float w3v = w1p[(k + 3) * HID];
#pragma unroll
            for (int r = 0; r < 8; ++r) {
                float4 c = *reinterpret_cast<const float4*>(&ctx_s[(rr * 8 + r) * CDIM + k]);
                acc[r] = fmaf(c.x, w0, acc[r]);
                acc[r] = fmaf(c.y, w1v, acc[r]);
                acc[r] = fmaf(c.z, w2v, acc[r]);
                acc[r] = fmaf(c.w, w3v, acc[r]);
            }
        }
#pragma unroll
        for (int r = 0; r < 8; ++r)
            hh1_s[(rr * 8 + r) * HID + o] = fmaxf(acc[r], 0.0f);
    }
    __syncthreads();

    // ---- GEMM2: hh2 = relu(hh1 @ W2 + b2), K=256 ----
    {
        const int o = t & 255, rr = t >> 8;
        const float* w2p = W2 + l * HID * HID + o;
        float acc[8];
        const float bias = b2[l * HID + o];
#pragma unroll
        for (int r = 0; r < 8; ++r) acc[r] = bias;
        for (int k = 0; k < HID; k += 4) {
            float w0 = w2p[(k + 0) * HID];
            float w1v = w2p[(k + 1) * HID];
            float w2v = w2p[(k + 2) * HID];
            float w3v = w2p[(k + 3) * HID];
#pragma unroll
            for (int r = 0; r < 8; ++r) {
                float4 c = *reinterpret_cast<const float4*>(&hh1_s[(rr * 8 + r) * HID + k]);
                acc[r] = fmaf(c.x, w0, acc[r]);
                acc[r] = fmaf(c.y, w1v, acc[r]);
                acc[r] = fmaf(c.z, w2v, acc[r]);
                acc[r] = fmaf(c.w, w3v, acc[r]);
            }
        }
#pragma unroll
        for (int r = 0; r < 8; ++r)
            hh2_s[(rr * 8 + r) * HID + o] = fmaxf(acc[r], 0.0f);
    }
    __syncthreads();

    // ---- GEMM3 + spline: each thread owns (2 rows, 1 dim) ----
    {
        const int d = t & 63;      // lane id == dim
        const int g = t >> 6;      // wave id 0..7 -> rows 2g, 2g+1
        const int r0 = 2 * g, r1 = 2 * g + 1;
        float a0[PPD], a1[PPD];
        const float* b3p = b3 + l * ODIM + d * PPD;
#pragma unroll
        for (int p = 0; p < PPD; ++p) { a0[p] = b3p[p]; a1[p] = a0[p]; }
        const float* wp = W3p + (size_t)(l * D + d) * HID * PPDP;
        for (int k = 0; k < HID; ++k) {
            float h0 = hh2_s[r0 * HID + k];
            float h1 = hh2_s[r1 * HID + k];
            const float4* w4 = reinterpret_cast<const float4*>(wp + k * PPDP);
            float w[PPDP];
#pragma unroll
            for (int q = 0; q < 6; ++q)
                *reinterpret_cast<float4*>(&w[q * 4]) = w4[q];
#pragma unroll
            for (int p = 0; p < PPD; ++p) {
                a0[p] = fmaf(h0, w[p], a0[p]);
                a1[p] = fmaf(h1, w[p], a1[p]);
            }
        }
        float x0 = x[(size_t)(rbase + r0) * D + d];
        float x1 = x[(size_t)(rbase + r1) * D + d];
        float y0, ld0, y1, ld1;
        rqs(x0, a0, y0, ld0);
        rqs(x1, a1, y1, ld1);
        y_s[r0 * D + d] = y0;
        y_s[r1 * D + d] = y1;
        float s0 = ld0, s1 = ld1;
#pragma unroll
        for (int off = 32; off; off >>= 1) {
            s0 += __shfl_xor(s0, off);
            s1 += __shfl_xor(s1, off);
        }
        if (d == 0) {
            logdet[rbase + r0] += s0;
            logdet[rbase + r1] += s1;
        }
    }
    __syncthreads();

    // ---- LU: x_new = A @ y + bias (A_t is transposed for coalesced reads) ----
    for (int pass = 0; pass < 2; ++pass) {
        int idx = pass * TB + t;           // 0..1023 -> (r, i)
        int r = idx >> 6, i = idx & 63;
        float acc = lu_bias[l * D + i];
        const float* ap = At + (size_t)l * D * D + i;
#pragma unroll 8
        for (int j = 0; j < D; ++j)
            acc = fmaf(y_s[r * D + j], ap[j * D], acc);
        x[(size_t)(rbase + r) * D + i] = acc;
    }
}

// ---------------- final: out = base + logdet ---------------------------------
__global__ void final_kernel(const float* __restrict__ x,
                             const float* __restrict__ logdet,
                             const float* __restrict__ lu_const,
                             float* __restrict__ out) {
    int t = threadIdx.x;
    int b = blockIdx.x * 4 + (t >> 6);
    int d = t & 63;
    float v = x[(size_t)b * D + d];
    float s = v * v;
#pragma unroll
    for (int off = 32; off; off >>= 1) s += __shfl_xor(s, off);
    if (d == 0)
        out[b] = logdet[b] + lu_const[0] - 0.5f * s - 0.5f * 64.0f * 1.8378770664093453f;
}

extern "C" void kernel_launch(void* const* d_in, const int* in_sizes, int n_in,
                              void* d_out, int out_size, void* d_ws, size_t ws_size,
                              hipStream_t stream) {
    const float* inputs  = (const float*)d_in[0];
    const float* context = (const float*)d_in[1];
    const float* W1      = (const float*)d_in[2];
    const float* b1      = (const float*)d_in[3];
    const float* W2      = (const float*)d_in[4];
    const float* b2      = (const float*)d_in[5];
    const float* W3      = (const float*)d_in[6];
    const float* b3      = (const float*)d_in[7];
    const float* lu_bias = (const float*)d_in[8];
    const float* lower_e = (const float*)d_in[9];
    const float* upper_e = (const float*)d_in[10];
    const float* udiag   = (const float*)d_in[11];
    float* out = (float*)d_out;

    char* ws = (char*)d_ws;
    float* x        = (float*)ws; ws += (size_t)BATCH * D * 4;
    float* logdet   = (float*)ws; ws += (size_t)BATCH * 4;
    float* At       = (float*)ws; ws += (size_t)NL * D * D * 4;
    float* lu_const = (float*)ws; ws += 16;
    float* W3p      = (float*)ws; ws += (size_t)NL * D * HID * PPDP * 4;

    init_kernel<<<(BATCH * D + 255) / 256, 256, 0, stream>>>(inputs, x, logdet);
    lu_prep<<<NL, 256, 0, stream>>>(lower_e, upper_e, udiag, At, lu_const);
    w3t_kernel<<<(NL * D * HID * PPDP + 255) / 256, 256, 0, stream>>>(W3, W3p);
    for (int l = 0; l < NL; ++l) {
        layer_kernel<<<BATCH / ROWS, TB, 0, stream>>>(
            context, W1, b1, W2, b2, W3p, b3, lu_bias, At, x, logdet, l);
    }
    final_kernel<<<BATCH / 4, 256, 0, stream>>>(x, logdet, lu_const, out);
}

// Round 2
// 1086.850 us; speedup vs baseline: 12.9102x; 12.9102x over previous
//
#include <hip/hip_runtime.h>
#include <hip/hip_bf16.h>
#include <math.h>

#define D 64
#define CDIM 128
#define NL 5
#define NB 8
#define HID 256
#define ODIM 1472      // D*(3*NB-1)
#define PPD 23
#define PPDP 24        // padded params per dim
#define NPAD 1536      // D*PPDP
#define NTRI 2016
#define BATCH 32768
#define CHUNK 8192

typedef unsigned short u16;
typedef __attribute__((ext_vector_type(8))) short bf16x8;
typedef __attribute__((ext_vector_type(8))) unsigned short u16x8;
typedef __attribute__((ext_vector_type(4))) float f32x4;

__device__ __forceinline__ float softplusf(float x) {
    return fmaxf(x, 0.0f) + log1pf(__expf(-fabsf(x)));
}
__device__ __forceinline__ u16 f2bf(float f) {
    __hip_bfloat16 h = __float2bfloat16(f);
    return *reinterpret_cast<u16*>(&h);
}
__device__ __forceinline__ float bf2f(u16 u) {
    return __uint_as_float(((unsigned int)u) << 16);
}

// global->LDS direct 16B load; LDS dest is wave-uniform base + lane*16.
__device__ __forceinline__ void gload16(const u16* g, const u16* s) {
    __builtin_amdgcn_global_load_lds(
        (const __attribute__((address_space(1))) unsigned int*)(unsigned long long)(uintptr_t)g,
        (__attribute__((address_space(3))) unsigned int*)(unsigned int)(uintptr_t)s,
        16, 0, 0);
}

// ---------------- prep: context -> bf16 --------------------------------------
__global__ void cvt_ctx(const float* __restrict__ c, u16* __restrict__ o) {
    int i = blockIdx.x * 256 + threadIdx.x;
    if (i < BATCH * CDIM) o[i] = f2bf(c[i]);
}

// ---------------- prep: W1t/W2t transposed bf16 ------------------------------
__global__ void prep_w12(const float* __restrict__ W1, const float* __restrict__ W2,
                         u16* __restrict__ W1t, u16* __restrict__ W2t) {
    int i = blockIdx.x * 256 + threadIdx.x;
    if (i < NL * HID * CDIM) {   // W1t[l][n][k] = W1[l][k][n]
        int k = i % CDIM; int n = (i / CDIM) % HID; int l = i / (CDIM * HID);
        W1t[i] = f2bf(W1[(l * CDIM + k) * HID + n]);
    }
    if (i < NL * HID * HID) {    // W2t[l][n][k] = W2[l][k][n]
        int k = i % HID; int n = (i / HID) % HID; int l = i / (HID * HID);
        W2t[i] = f2bf(W2[(l * HID + k) * HID + n]);
    }
}

// ---------------- prep: W3t padded/transposed + padded bias ------------------
__global__ void prep_w3(const float* __restrict__ W3, const float* __restrict__ b3,
                        u16* __restrict__ W3t, float* __restrict__ b3p) {
    int i = blockIdx.x * 256 + threadIdx.x;
    if (i < NL * NPAD * HID) {   // W3t[l][n][k], n = d*24+p
        int k = i % HID; int n = (i / HID) % NPAD; int l = i / (HID * NPAD);
        int dd = n / PPDP, p = n % PPDP;
        W3t[i] = (p < PPD) ? f2bf(W3[(l * HID + k) * ODIM + dd * PPD + p]) : (u16)0;
    }
    if (i < NL * NPAD) {
        int n = i % NPAD; int l = i / NPAD;
        int dd = n / PPDP, p = n % PPDP;
        b3p[i] = (p < PPD) ? b3[l * ODIM + dd * PPD + p] : 0.0f;
    }
}

// ---------------- precompute: A_t = (L@U)^T per layer, total LU logdet -------
__global__ void lu_prep(const float* __restrict__ lower_e,
                        const float* __restrict__ upper_e,
                        const float* __restrict__ udiag,
                        float* __restrict__ At, float* __restrict__ lu_const) {
    int l = blockIdx.x;
    int t = threadIdx.x;
    __shared__ float Ls[D * D];
    __shared__ float Us[D * D];
    for (int idx = t; idx < D * D; idx += 256) {
        int i = idx >> 6, j = idx & 63;
        float lv;
        if (i == j)      lv = 1.0f;
        else if (i > j)  lv = lower_e[l * NTRI + (i * (i - 1)) / 2 + j];
        else             lv = 0.0f;
        Ls[idx] = lv;
        float uv;
        if (i == j)      uv = softplusf(udiag[l * D + i]) + 0.001f;
        else if (j > i)  uv = upper_e[l * NTRI + i * (D - 1) - (i * (i - 1)) / 2 + (j - i - 1)];
        else             uv = 0.0f;
        Us[idx] = uv;
    }
    __syncthreads();
    for (int idx = t; idx < D * D; idx += 256) {
        int i = idx >> 6, j = idx & 63;
        float acc = 0.0f;
        int km = min(i, j);
        for (int k = 0; k <= km; ++k) acc += Ls[i * D + k] * Us[k * D + j];
        At[(l * D + j) * D + i] = acc;   // transposed store
    }
    if (l == 0 && t == 0) {
        float s = 0.0f;
        for (int ll = 0; ll < NL; ++ll)
            for (int k = 0; k < D; ++k)
                s += __logf(softplusf(udiag[ll * D + k]) + 0.001f);
        lu_const[0] = s;
    }
}

// ---------------- init: copy x, zero logdet ----------------------------------
__global__ void init_kernel(const float* __restrict__ inp, float* __restrict__ x,
                            float* __restrict__ logdet) {
    int i = blockIdx.x * 256 + threadIdx.x;
    if (i < BATCH * D) x[i] = inp[i];
    if (i < BATCH) logdet[i] = 0.0f;
}

// ---------------- MFMA GEMM: C = [relu](A @ Bt^T + bias), bf16 in/out --------
// A [M][K] bf16 row-major, Bt [N][K] bf16 row-major, 128x128 tile, BK=64.
// LDS XOR-swizzle (slot ^= row&7) applied on pre-swizzled global source and on
// ds_read address (rule #21: linear gload_lds dest + inverse-swz source).
template<int RELU>
__global__ __launch_bounds__(256) void gemm_bf16(
    const u16* __restrict__ A, const u16* __restrict__ Bt,
    const float* __restrict__ bias, u16* __restrict__ Cv,
    int N, int K)
{
    __shared__ u16 lds[16384];   // A: [0,8192) ushorts (16KB), B: [8192,16384)
    const int t = threadIdx.x;
    const int w = t >> 6, l = t & 63;
    const int wm = w >> 1, wn = w & 1;
    const size_t m0 = (size_t)blockIdx.x * 128;
    const int n0 = blockIdx.y * 128;
    const int lrow = l & 15, lk = l >> 4;
    const int srow = l >> 3, sslot = l & 7;

    f32x4 acc[4][4] = {};

    for (int k0 = 0; k0 < K; k0 += 64) {
        // stage A tile (128x64 bf16 = 16KB = 16 chunks of 1KB)
#pragma unroll
        for (int q = 0; q < 4; ++q) {
            int c = q * 4 + w;
            int row = c * 8 + srow;
            int slog = sslot ^ (row & 7);
            gload16(A + (m0 + row) * K + k0 + slog * 8, &lds[c * 512]);
        }
        // stage B tile (128x64 bf16 = 16KB)
#pragma unroll
        for (int q = 0; q < 4; ++q) {
            int c = q * 4 + w;
            int row = c * 8 + srow;
            int slog = sslot ^ (row & 7);
            gload16(Bt + (size_t)(n0 + row) * K + k0 + slog * 8, &lds[8192 + c * 512]);
        }
        __syncthreads();
#pragma unroll
        for (int ks = 0; ks < 2; ++ks) {
            bf16x8 a[4], b[4];
#pragma unroll
            for (int mf = 0; mf < 4; ++mf) {
                int row = wm * 64 + mf * 16 + lrow;
                int slot = (ks * 4 + lk) ^ (row & 7);
                a[mf] = *(const bf16x8*)&lds[row * 64 + slot * 8];
            }
#pragma unroll
            for (int nf = 0; nf < 4; ++nf) {
                int row = wn * 64 + nf * 16 + lrow;
                int slot = (ks * 4 + lk) ^ (row & 7);
                b[nf] = *(const bf16x8*)&lds[8192 + row * 64 + slot * 8];
            }
#pragma unroll
            for (int mf = 0; mf < 4; ++mf)
#pragma unroll
                for (int nf = 0; nf < 4; ++nf)
                    acc[mf][nf] = __builtin_amdgcn_mfma_f32_16x16x32_bf16(
                        a[mf], b[nf], acc[mf][nf], 0, 0, 0);
        }
        __syncthreads();
    }
    // epilogue: D frag row=(l>>4)*4+i, col=l&15  [m89/m91 verified]
#pragma unroll
    for (int nf = 0; nf < 4; ++nf) {
        int col = n0 + wn * 64 + nf * 16 + lrow;
        float bv = bias[col];
#pragma unroll
        for (int mf = 0; mf < 4; ++mf) {
            size_t rbase = m0 + wm * 64 + mf * 16 + lk * 4;
#pragma unroll
            for (int i = 0; i < 4; ++i) {
                float v = acc[mf][nf][i] + bv;
                if (RELU) v = fmaxf(v, 0.0f);
                Cv[(rbase + i) * N + col] = f2bf(v);
            }
        }
    }
}

// ---------------- spline helpers ---------------------------------------------
__device__ __forceinline__ void cumbins(const float* pp, float* c) {
    float m = pp[0];
#pragma unroll
    for (int i = 1; i < NB; ++i) m = fmaxf(m, pp[i]);
    float e[NB];
    float s = 0.0f;
#pragma unroll
    for (int i = 0; i < NB; ++i) { e[i] = __expf(pp[i] - m); s += e[i]; }
    float inv = 1.0f / s;
    c[0] = -5.0f;
    float run = 0.0f;
#pragma unroll
    for (int i = 0; i < NB - 1; ++i) {
        run += fmaf(0.992f, e[i] * inv, 0.001f);
        c[i + 1] = fmaf(10.0f, run, -5.0f);
    }
    c[NB] = 5.0f;
}

__device__ __forceinline__ void rqs(float xv, const float* pp, float& yo, float& ldo) {
    const float Bnd = 5.0f;
    float cw[NB + 1], ch[NB + 1], dv[NB + 1];
    cumbins(pp, cw);
    cumbins(pp + NB, ch);
    dv[0] = 1.0f; dv[NB] = 1.0f;
#pragma unroll
    for (int i = 1; i < NB; ++i) dv[i] = 0.001f + softplusf(pp[15 + i]);
    float xc = fminf(fmaxf(xv, -Bnd), Bnd);
    float icw = cw[0], icw1 = cw[1], ich = ch[0], ich1 = ch[1], d0 = dv[0], d1 = dv[1];
#pragma unroll
    for (int kk = 1; kk < NB; ++kk) {
        bool sel = (xc >= cw[kk]);
        icw  = sel ? cw[kk]     : icw;
        icw1 = sel ? cw[kk + 1] : icw1;
        ich  = sel ? ch[kk]     : ich;
        ich1 = sel ? ch[kk + 1] : ich1;
        d0   = sel ? dv[kk]     : d0;
        d1   = sel ? dv[kk + 1] : d1;
    }
    float iw  = icw1 - icw;
    float ih  = ich1 - ich;
    float dlt = ih / iw;
    float th  = (xc - icw) / iw;
    float omt = 1.0f - th;
    float tomt = th * omt;
    float numer = ih * (dlt * th * th + d0 * tomt);
    float den = dlt + (d0 + d1 - 2.0f * dlt) * tomt;
    float outv = ich + numer / den;
    float dnum = dlt * dlt * (d1 * th * th + 2.0f * dlt * tomt + d0 * omt * omt);
    float ld = __logf(dnum) - 2.0f * __logf(den);
    bool inside = (xv >= -Bnd) && (xv <= Bnd);
    yo  = inside ? outv : xv;
    ldo = inside ? ld : 0.0f;
}

// ---------------- spline + LU (params materialized, bf16) --------------------
__global__ __launch_bounds__(512) void spline_lu_kernel(
    const u16* __restrict__ params,   // [CHUNK][NPAD] bf16, chunk-local
    const float* __restrict__ At, const float* __restrict__ lu_bias,
    float* __restrict__ x, float* __restrict__ logdet,
    int l, int row_base)
{
    __shared__ float y_s[16 * D];
    const int t = threadIdx.x;
    const int d = t & 63, g = t >> 6;
    const int lr0 = 2 * g, lr1 = lr0 + 1;
    const size_t cr0 = (size_t)blockIdx.x * 16 + lr0;
    const size_t gr0 = (size_t)row_base + cr0;

    float a0[PPD], a1[PPD];
    {
        const u16x8* p0 = (const u16x8*)(params + cr0 * NPAD + d * PPDP);
        const u16x8* p1 = (const u16x8*)(params + (cr0 + 1) * NPAD + d * PPDP);
        u16x8 v0 = p0[0], v1 = p0[1], v2 = p0[2];
        u16x8 w0 = p1[0], w1 = p1[1], w2 = p1[2];
#pragma unroll
        for (int j = 0; j < 8; ++j) { a0[j] = bf2f(v0[j]); a1[j] = bf2f(w0[j]); }
#pragma unroll
        for (int j = 0; j < 8; ++j) { a0[8 + j] = bf2f(v1[j]); a1[8 + j] = bf2f(w1[j]); }
#pragma unroll
        for (int j = 0; j < 7; ++j) { a0[16 + j] = bf2f(v2[j]); a1[16 + j] = bf2f(w2[j]); }
    }
    float x0 = x[gr0 * D + d];
    float x1 = x[(gr0 + 1) * D + d];
    float y0, ld0, y1, ld1;
    rqs(x0, a0, y0, ld0);
    rqs(x1, a1, y1, ld1);
    y_s[lr0 * D + d] = y0;
    y_s[lr1 * D + d] = y1;
    float s0 = ld0, s1 = ld1;
#pragma unroll
    for (int off = 32; off; off >>= 1) {
        s0 += __shfl_xor(s0, off);
        s1 += __shfl_xor(s1, off);
    }
    if (d == 0) {
        logdet[gr0] += s0;
        logdet[gr0 + 1] += s1;
    }
    __syncthreads();
    // LU: x_new = A @ y + bias (At transposed for coalesced reads)
    for (int pass = 0; pass < 2; ++pass) {
        int idx = pass * 512 + t;
        int r = idx >> 6, i = idx & 63;
        float acc = lu_bias[l * D + i];
        const float* ap = At + (size_t)l * D * D + i;
#pragma unroll 8
        for (int j = 0; j < D; ++j)
            acc = fmaf(y_s[r * D + j], ap[j * D], acc);
        x[((size_t)row_base + blockIdx.x * 16 + r) * D + i] = acc;
    }
}

// ---------------- final: out = base + logdet ---------------------------------
__global__ void final_kernel(const float* __restrict__ x,
                             const float* __restrict__ logdet,
                             const float* __restrict__ lu_const,
                             float* __restrict__ out) {
    int t = threadIdx.x;
    int b = blockIdx.x * 4 + (t >> 6);
    int d = t & 63;
    float v = x[(size_t)b * D + d];
    float s = v * v;
#pragma unroll
    for (int off = 32; off; off >>= 1) s += __shfl_xor(s, off);
    if (d == 0)
        out[b] = logdet[b] + lu_const[0] - 0.5f * s - 0.5f * 64.0f * 1.8378770664093453f;
}

extern "C" void kernel_launch(void* const* d_in, const int* in_sizes, int n_in,
                              void* d_out, int out_size, void* d_ws, size_t ws_size,
                              hipStream_t stream) {
    const float* inputs  = (const float*)d_in[0];
    const float* context = (const float*)d_in[1];
    const float* W1      = (const float*)d_in[2];
    const float* b1      = (const float*)d_in[3];
    const float* W2      = (const float*)d_in[4];
    const float* b2      = (const float*)d_in[5];
    const float* W3      = (const float*)d_in[6];
    const float* b3      = (const float*)d_in[7];
    const float* lu_bias = (const float*)d_in[8];
    const float* lower_e = (const float*)d_in[9];
    const float* upper_e = (const float*)d_in[10];
    const float* udiag   = (const float*)d_in[11];
    float* out = (float*)d_out;

    char* p = (char*)d_ws;
    auto alloc = [&](size_t bytes) { void* r = p; p += (bytes + 255) & ~(size_t)255; return r; };
    float* x        = (float*)alloc((size_t)BATCH * D * 4);
    float* logdet   = (float*)alloc((size_t)BATCH * 4);
    float* At       = (float*)alloc((size_t)NL * D * D * 4);
    float* lu_const = (float*)alloc(256);
    u16*   ctx_bf   = (u16*)alloc((size_t)BATCH * CDIM * 2);
    u16*   hh1      = (u16*)alloc((size_t)BATCH * HID * 2);
    u16*   hh2      = (u16*)alloc((size_t)BATCH * HID * 2);
    u16*   W1t      = (u16*)alloc((size_t)NL * HID * CDIM * 2);
    u16*   W2t      = (u16*)alloc((size_t)NL * HID * HID * 2);
    u16*   W3t      = (u16*)alloc((size_t)NL * NPAD * HID * 2);
    float* b3p      = (float*)alloc((size_t)NL * NPAD * 4);
    u16*   paramsB  = (u16*)alloc((size_t)CHUNK * NPAD * 2);

    cvt_ctx<<<(BATCH * CDIM + 255) / 256, 256, 0, stream>>>(context, ctx_bf);
    prep_w12<<<(NL * HID * HID + 255) / 256, 256, 0, stream>>>(W1, W2, W1t, W2t);
    prep_w3<<<(NL * NPAD * HID + 255) / 256, 256, 0, stream>>>(W3, b3, W3t, b3p);
    lu_prep<<<NL, 256, 0, stream>>>(lower_e, upper_e, udiag, At, lu_const);
    init_kernel<<<(BATCH * D + 255) / 256, 256, 0, stream>>>(inputs, x, logdet);

    for (int l = 0; l < NL; ++l) {
        gemm_bf16<1><<<dim3(BATCH / 128, HID / 128), 256, 0, stream>>>(
            ctx_bf, W1t + (size_t)l * HID * CDIM, b1 + l * HID, hh1, HID, CDIM);
        gemm_bf16<1><<<dim3(BATCH / 128, HID / 128), 256, 0, stream>>>(
            hh1, W2t + (size_t)l * HID * HID, b2 + l * HID, hh2, HID, HID);
        for (int c = 0; c < BATCH / CHUNK; ++c) {
            gemm_bf16<0><<<dim3(CHUNK / 128, NPAD / 128), 256, 0, stream>>>(
                hh2 + (size_t)c * CHUNK * HID, W3t + (size_t)l * NPAD * HID,
                b3p + l * NPAD, paramsB, NPAD, HID);
            spline_lu_kernel<<<CHUNK / 16, 512, 0, stream>>>(
                paramsB, At, lu_bias, x, logdet, l, c * CHUNK);
        }
    }
    final_kernel<<<BATCH / 4, 256, 0, stream>>>(x, logdet, lu_const, out);
}

// Round 3
// 738.789 us; speedup vs baseline: 18.9924x; 1.4711x over previous
//
#include <hip/hip_runtime.h>
#include <hip/hip_bf16.h>
#include <math.h>

#define D 64
#define CDIM 128
#define NL 5
#define NB 8
#define HID 256
#define ODIM 1472      // D*(3*NB-1)
#define PPD 23
#define PPDP 24        // padded params per dim
#define NPAD 1536      // D*PPDP
#define NTRI 2016
#define BATCH 32768
#define CHUNK 8192     // fallback chunk if ws too small for full batch

typedef unsigned short u16;
typedef __attribute__((ext_vector_type(8))) short bf16x8;
typedef __attribute__((ext_vector_type(8))) unsigned short u16x8;
typedef __attribute__((ext_vector_type(4))) float f32x4;

__device__ __forceinline__ float softplusf(float x) {
    return fmaxf(x, 0.0f) + log1pf(__expf(-fabsf(x)));
}
__device__ __forceinline__ u16 f2bf(float f) {
    __hip_bfloat16 h = __float2bfloat16(f);
    return *reinterpret_cast<u16*>(&h);
}
__device__ __forceinline__ float bf2f(u16 u) {
    return __uint_as_float(((unsigned int)u) << 16);
}

// global->LDS direct 16B load; LDS dest is wave-uniform base + lane*16.
__device__ __forceinline__ void gload16(const u16* g, const u16* s) {
    __builtin_amdgcn_global_load_lds(
        (const __attribute__((address_space(1))) unsigned int*)(unsigned long long)(uintptr_t)g,
        (__attribute__((address_space(3))) unsigned int*)(unsigned int)(uintptr_t)s,
        16, 0, 0);
}

// bijective XCD-chunked swizzle (m204): contiguous grid chunk per XCD
__device__ __forceinline__ int xcd_swz(int bid, int nwg) {
    int q = nwg >> 3, r = nwg & 7;
    int xcd = bid & 7, idx = bid >> 3;
    return (xcd < r ? xcd * (q + 1) : r * (q + 1) + (xcd - r) * q) + idx;
}

// ---------------- prep: context -> bf16 --------------------------------------
__global__ void cvt_ctx(const float* __restrict__ c, u16* __restrict__ o) {
    int i = blockIdx.x * 256 + threadIdx.x;
    if (i < BATCH * CDIM) o[i] = f2bf(c[i]);
}

// ---------------- prep: W1t/W2t transposed bf16 ------------------------------
__global__ void prep_w12(const float* __restrict__ W1, const float* __restrict__ W2,
                         u16* __restrict__ W1t, u16* __restrict__ W2t) {
    int i = blockIdx.x * 256 + threadIdx.x;
    if (i < NL * HID * CDIM) {   // W1t[l][n][k] = W1[l][k][n]
        int k = i % CDIM; int n = (i / CDIM) % HID; int l = i / (CDIM * HID);
        W1t[i] = f2bf(W1[(l * CDIM + k) * HID + n]);
    }
    if (i < NL * HID * HID) {    // W2t[l][n][k] = W2[l][k][n]
        int k = i % HID; int n = (i / HID) % HID; int l = i / (HID * HID);
        W2t[i] = f2bf(W2[(l * HID + k) * HID + n]);
    }
}

// ---------------- prep: W3t padded/transposed + padded bias ------------------
__global__ void prep_w3(const float* __restrict__ W3, const float* __restrict__ b3,
                        u16* __restrict__ W3t, float* __restrict__ b3p) {
    int i = blockIdx.x * 256 + threadIdx.x;
    if (i < NL * NPAD * HID) {   // W3t[l][n][k], n = d*24+p
        int k = i % HID; int n = (i / HID) % NPAD; int l = i / (HID * NPAD);
        int dd = n / PPDP, p = n % PPDP;
        W3t[i] = (p < PPD) ? f2bf(W3[(l * HID + k) * ODIM + dd * PPD + p]) : (u16)0;
    }
    if (i < NL * NPAD) {
        int n = i % NPAD; int l = i / NPAD;
        int dd = n / PPDP, p = n % PPDP;
        b3p[i] = (p < PPD) ? b3[l * ODIM + dd * PPD + p] : 0.0f;
    }
}

// ---------------- precompute: A_t = (L@U)^T per layer, total LU logdet -------
__global__ void lu_prep(const float* __restrict__ lower_e,
                        const float* __restrict__ upper_e,
                        const float* __restrict__ udiag,
                        float* __restrict__ At, float* __restrict__ lu_const) {
    int l = blockIdx.x;
    int t = threadIdx.x;
    __shared__ float Ls[D * D];
    __shared__ float Us[D * D];
    __shared__ float red[4];
    for (int idx = t; idx < D * D; idx += 256) {
        int i = idx >> 6, j = idx & 63;
        float lv;
        if (i == j)      lv = 1.0f;
        else if (i > j)  lv = lower_e[l * NTRI + (i * (i - 1)) / 2 + j];
        else             lv = 0.0f;
        Ls[idx] = lv;
        float uv;
        if (i == j)      uv = softplusf(udiag[l * D + i]) + 0.001f;
        else if (j > i)  uv = upper_e[l * NTRI + i * (D - 1) - (i * (i - 1)) / 2 + (j - i - 1)];
        else             uv = 0.0f;
        Us[idx] = uv;
    }
    __syncthreads();
    for (int idx = t; idx < D * D; idx += 256) {
        int i = idx >> 6, j = idx & 63;
        float acc = 0.0f;
        int km = min(i, j);
        for (int k = 0; k <= km; ++k) acc += Ls[i * D + k] * Us[k * D + j];
        At[(l * D + j) * D + i] = acc;   // transposed store
    }
    // parallel log-sum reduction (was 320 serial loads+logs on one lane: ~160us)
    if (l == 0) {
        float s = 0.0f;
        for (int i = t; i < NL * D; i += 256)
            s += __logf(softplusf(udiag[i]) + 0.001f);
#pragma unroll
        for (int off = 32; off; off >>= 1) s += __shfl_xor(s, off);
        if ((t & 63) == 0) red[t >> 6] = s;
        __syncthreads();
        if (t == 0) lu_const[0] = red[0] + red[1] + red[2] + red[3];
    }
}

// ---------------- init: copy x, zero logdet ----------------------------------
__global__ void init_kernel(const float* __restrict__ inp, float* __restrict__ x,
                            float* __restrict__ logdet) {
    int i = blockIdx.x * 256 + threadIdx.x;
    if (i < BATCH * D) x[i] = inp[i];
    if (i < BATCH) logdet[i] = 0.0f;
}

// ---------------- MFMA GEMM: C = [relu](A @ Bt^T + bias), bf16 in/out --------
// A [M][K] bf16 row-major, Bt [N][K] bf16 row-major, 128x128 tile, BK=64.
// Flattened grid (col-tile fastest) + XCD-chunked swizzle: consecutive blocks
// on one XCD share the A-panel -> L2 A-reuse. LDS XOR-swizzle per rule #21.
template<int RELU>
__global__ __launch_bounds__(256) void gemm_bf16(
    const u16* __restrict__ A, const u16* __restrict__ Bt,
    const float* __restrict__ bias, u16* __restrict__ Cv,
    int N, int K, int ncol)
{
    __shared__ u16 lds[16384];   // A: [0,8192) ushorts (16KB), B: [8192,16384)
    const int t = threadIdx.x;
    const int w = t >> 6, l = t & 63;
    const int wm = w >> 1, wn = w & 1;
    const int wg = xcd_swz(blockIdx.x, gridDim.x);
    const size_t m0 = (size_t)(wg / ncol) * 128;
    const int n0 = (wg % ncol) * 128;
    const int lrow = l & 15, lk = l >> 4;
    const int srow = l >> 3, sslot = l & 7;

    f32x4 acc[4][4] = {};

    for (int k0 = 0; k0 < K; k0 += 64) {
        // stage A tile (128x64 bf16 = 16KB = 16 chunks of 1KB)
#pragma unroll
        for (int q = 0; q < 4; ++q) {
            int c = q * 4 + w;
            int row = c * 8 + srow;
            int slog = sslot ^ (row & 7);
            gload16(A + (m0 + row) * K + k0 + slog * 8, &lds[c * 512]);
        }
        // stage B tile (128x64 bf16 = 16KB)
#pragma unroll
        for (int q = 0; q < 4; ++q) {
            int c = q * 4 + w;
            int row = c * 8 + srow;
            int slog = sslot ^ (row & 7);
            gload16(Bt + (size_t)(n0 + row) * K + k0 + slog * 8, &lds[8192 + c * 512]);
        }
        __syncthreads();
#pragma unroll
        for (int ks = 0; ks < 2; ++ks) {
            bf16x8 a[4], b[4];
#pragma unroll
            for (int mf = 0; mf < 4; ++mf) {
                int row = wm * 64 + mf * 16 + lrow;
                int slot = (ks * 4 + lk) ^ (row & 7);
                a[mf] = *(const bf16x8*)&lds[row * 64 + slot * 8];
            }
#pragma unroll
            for (int nf = 0; nf < 4; ++nf) {
                int row = wn * 64 + nf * 16 + lrow;
                int slot = (ks * 4 + lk) ^ (row & 7);
                b[nf] = *(const bf16x8*)&lds[8192 + row * 64 + slot * 8];
            }
#pragma unroll
            for (int mf = 0; mf < 4; ++mf)
#pragma unroll
                for (int nf = 0; nf < 4; ++nf)
                    acc[mf][nf] = __builtin_amdgcn_mfma_f32_16x16x32_bf16(
                        a[mf], b[nf], acc[mf][nf], 0, 0, 0);
        }
        __syncthreads();
    }
    // epilogue: D frag row=(l>>4)*4+i, col=l&15  [m89/m91 verified]
#pragma unroll
    for (int nf = 0; nf < 4; ++nf) {
        int col = n0 + wn * 64 + nf * 16 + lrow;
        float bv = bias[col];
#pragma unroll
        for (int mf = 0; mf < 4; ++mf) {
            size_t rbase = m0 + wm * 64 + mf * 16 + lk * 4;
#pragma unroll
            for (int i = 0; i < 4; ++i) {
                float v = acc[mf][nf][i] + bv;
                if (RELU) v = fmaxf(v, 0.0f);
                Cv[(rbase + i) * N + col] = f2bf(v);
            }
        }
    }
}

// ---------------- spline helpers ---------------------------------------------
__device__ __forceinline__ void cumbins(const float* pp, float* c) {
    float m = pp[0];
#pragma unroll
    for (int i = 1; i < NB; ++i) m = fmaxf(m, pp[i]);
    float e[NB];
    float s = 0.0f;
#pragma unroll
    for (int i = 0; i < NB; ++i) { e[i] = __expf(pp[i] - m); s += e[i]; }
    float inv = 1.0f / s;
    c[0] = -5.0f;
    float run = 0.0f;
#pragma unroll
    for (int i = 0; i < NB - 1; ++i) {
        run += fmaf(0.992f, e[i] * inv, 0.001f);
        c[i + 1] = fmaf(10.0f, run, -5.0f);
    }
    c[NB] = 5.0f;
}

__device__ __forceinline__ void rqs(float xv, const float* pp, float& yo, float& ldo) {
    const float Bnd = 5.0f;
    float cw[NB + 1], ch[NB + 1], dv[NB + 1];
    cumbins(pp, cw);
    cumbins(pp + NB, ch);
    dv[0] = 1.0f; dv[NB] = 1.0f;
#pragma unroll
    for (int i = 1; i < NB; ++i) dv[i] = 0.001f + softplusf(pp[15 + i]);
    float xc = fminf(fmaxf(xv, -Bnd), Bnd);
    float icw = cw[0], icw1 = cw[1], ich = ch[0], ich1 = ch[1], d0 = dv[0], d1 = dv[1];
#pragma unroll
    for (int kk = 1; kk < NB; ++kk) {
        bool sel = (xc >= cw[kk]);
        icw  = sel ? cw[kk]     : icw;
        icw1 = sel ? cw[kk + 1] : icw1;
        ich  = sel ? ch[kk]     : ich;
        ich1 = sel ? ch[kk + 1] : ich1;
        d0   = sel ? dv[kk]     : d0;
        d1   = sel ? dv[kk + 1] : d1;
    }
    float iw  = icw1 - icw;
    float ih  = ich1 - ich;
    float dlt = ih / iw;
    float th  = (xc - icw) / iw;
    float omt = 1.0f - th;
    float tomt = th * omt;
    float numer = ih * (dlt * th * th + d0 * tomt);
    float den = dlt + (d0 + d1 - 2.0f * dlt) * tomt;
    float outv = ich + numer / den;
    float dnum = dlt * dlt * (d1 * th * th + 2.0f * dlt * tomt + d0 * omt * omt);
    float ld = __logf(dnum) - 2.0f * __logf(den);
    bool inside = (xv >= -Bnd) && (xv <= Bnd);
    yo  = inside ? outv : xv;
    ldo = inside ? ld : 0.0f;
}

// ---------------- spline + LU (params materialized, bf16) --------------------
__global__ __launch_bounds__(512) void spline_lu_kernel(
    const u16* __restrict__ params,   // [chunk][NPAD] bf16, chunk-local
    const float* __restrict__ At, const float* __restrict__ lu_bias,
    float* __restrict__ x, float* __restrict__ logdet,
    int l, int row_base)
{
    __shared__ float y_s[16 * D];
    const int t = threadIdx.x;
    const int d = t & 63, g = t >> 6;
    const int lr0 = 2 * g, lr1 = lr0 + 1;
    const size_t cr0 = (size_t)blockIdx.x * 16 + lr0;
    const size_t gr0 = (size_t)row_base + cr0;

    float a0[PPD], a1[PPD];
    {
        const u16x8* p0 = (const u16x8*)(params + cr0 * NPAD + d * PPDP);
        const u16x8* p1 = (const u16x8*)(params + (cr0 + 1) * NPAD + d * PPDP);
        u16x8 v0 = p0[0], v1 = p0[1], v2 = p0[2];
        u16x8 w0 = p1[0], w1 = p1[1], w2 = p1[2];
#pragma unroll
        for (int j = 0; j < 8; ++j) { a0[j] = bf2f(v0[j]); a1[j] = bf2f(w0[j]); }
#pragma unroll
        for (int j = 0; j < 8; ++j) { a0[8 + j] = bf2f(v1[j]); a1[8 + j] = bf2f(w1[j]); }
#pragma unroll
        for (int j = 0; j < 7; ++j) { a0[16 + j] = bf2f(v2[j]); a1[16 + j] = bf2f(w2[j]); }
    }
    float x0 = x[gr0 * D + d];
    float x1 = x[(gr0 + 1) * D + d];
    float y0, ld0, y1, ld1;
    rqs(x0, a0, y0, ld0);
    rqs(x1, a1, y1, ld1);
    y_s[lr0 * D + d] = y0;
    y_s[lr1 * D + d] = y1;
    float s0 = ld0, s1 = ld1;
#pragma unroll
    for (int off = 32; off; off >>= 1) {
        s0 += __shfl_xor(s0, off);
        s1 += __shfl_xor(s1, off);
    }
    if (d == 0) {
        logdet[gr0] += s0;
        logdet[gr0 + 1] += s1;
    }
    __syncthreads();
    // LU: x_new = A @ y + bias (At transposed for coalesced reads)
    for (int pass = 0; pass < 2; ++pass) {
        int idx = pass * 512 + t;
        int r = idx >> 6, i = idx & 63;
        float acc = lu_bias[l * D + i];
        const float* ap = At + (size_t)l * D * D + i;
#pragma unroll 8
        for (int j = 0; j < D; ++j)
            acc = fmaf(y_s[r * D + j], ap[j * D], acc);
        x[((size_t)row_base + blockIdx.x * 16 + r) * D + i] = acc;
    }
}

// ---------------- final: out = base + logdet ---------------------------------
__global__ void final_kernel(const float* __restrict__ x,
                             const float* __restrict__ logdet,
                             const float* __restrict__ lu_const,
                             float* __restrict__ out) {
    int t = threadIdx.x;
    int b = blockIdx.x * 4 + (t >> 6);
    int d = t & 63;
    float v = x[(size_t)b * D + d];
    float s = v * v;
#pragma unroll
    for (int off = 32; off; off >>= 1) s += __shfl_xor(s, off);
    if (d == 0)
        out[b] = logdet[b] + lu_const[0] - 0.5f * s - 0.5f * 64.0f * 1.8378770664093453f;
}

extern "C" void kernel_launch(void* const* d_in, const int* in_sizes, int n_in,
                              void* d_out, int out_size, void* d_ws, size_t ws_size,
                              hipStream_t stream) {
    const float* inputs  = (const float*)d_in[0];
    const float* context = (const float*)d_in[1];
    const float* W1      = (const float*)d_in[2];
    const float* b1      = (const float*)d_in[3];
    const float* W2      = (const float*)d_in[4];
    const float* b2      = (const float*)d_in[5];
    const float* W3      = (const float*)d_in[6];
    const float* b3      = (const float*)d_in[7];
    const float* lu_bias = (const float*)d_in[8];
    const float* lower_e = (const float*)d_in[9];
    const float* upper_e = (const float*)d_in[10];
    const float* udiag   = (const float*)d_in[11];
    float* out = (float*)d_out;

    char* p = (char*)d_ws;
    auto alloc = [&](size_t bytes) { void* r = p; p += (bytes + 255) & ~(size_t)255; return r; };
    float* x        = (float*)alloc((size_t)BATCH * D * 4);
    float* logdet   = (float*)alloc((size_t)BATCH * 4);
    float* At       = (float*)alloc((size_t)NL * D * D * 4);
    float* lu_const = (float*)alloc(256);
    u16*   ctx_bf   = (u16*)alloc((size_t)BATCH * CDIM * 2);
    u16*   hh1      = (u16*)alloc((size_t)BATCH * HID * 2);
    u16*   hh2      = (u16*)alloc((size_t)BATCH * HID * 2);
    u16*   W1t      = (u16*)alloc((size_t)NL * HID * CDIM * 2);
    u16*   W2t      = (u16*)alloc((size_t)NL * HID * HID * 2);
    u16*   W3t      = (u16*)alloc((size_t)NL * NPAD * HID * 2);
    float* b3p      = (float*)alloc((size_t)NL * NPAD * 4);

    // full-batch params if ws allows (one GEMM3+spline dispatch per layer)
    size_t used = (size_t)(p - (char*)d_ws);
    int chunk = (ws_size - used >= (size_t)BATCH * NPAD * 2 + 256) ? BATCH : CHUNK;
    u16* paramsB = (u16*)alloc((size_t)chunk * NPAD * 2);

    cvt_ctx<<<(BATCH * CDIM + 255) / 256, 256, 0, stream>>>(context, ctx_bf);
    prep_w12<<<(NL * HID * HID + 255) / 256, 256, 0, stream>>>(W1, W2, W1t, W2t);
    prep_w3<<<(NL * NPAD * HID + 255) / 256, 256, 0, stream>>>(W3, b3, W3t, b3p);
    lu_prep<<<NL, 256, 0, stream>>>(lower_e, upper_e, udiag, At, lu_const);
    init_kernel<<<(BATCH * D + 255) / 256, 256, 0, stream>>>(inputs, x, logdet);

    for (int l = 0; l < NL; ++l) {
        gemm_bf16<1><<<(BATCH / 128) * 2, 256, 0, stream>>>(
            ctx_bf, W1t + (size_t)l * HID * CDIM, b1 + l * HID, hh1, HID, CDIM, 2);
        gemm_bf16<1><<<(BATCH / 128) * 2, 256, 0, stream>>>(
            hh1, W2t + (size_t)l * HID * HID, b2 + l * HID, hh2, HID, HID, 2);
        for (int c = 0; c < BATCH / chunk; ++c) {
            gemm_bf16<0><<<(chunk / 128) * (NPAD / 128), 256, 0, stream>>>(
                hh2 + (size_t)c * chunk * HID, W3t + (size_t)l * NPAD * HID,
                b3p + l * NPAD, paramsB, NPAD, HID, NPAD / 128);
            spline_lu_kernel<<<chunk / 16, 512, 0, stream>>>(
                paramsB, At, lu_bias, x, logdet, l, c * chunk);
        }
    }
    final_kernel<<<BATCH / 4, 256, 0, stream>>>(x, logdet, lu_const, out);
}

// Round 4
// 550.720 us; speedup vs baseline: 25.4783x; 1.3415x over previous
//
#include <hip/hip_runtime.h>
#include <hip/hip_bf16.h>
#include <math.h>

#define D 64
#define CDIM 128
#define NL 5
#define NB 8
#define HID 256
#define ODIM 1472      // D*(3*NB-1)
#define PPD 23
#define PPDP 24        // padded params per dim
#define NPAD 1536      // D*PPDP
#define NTRI 2016
#define BATCH 32768
#define CHUNK 8192     // fallback chunk if ws too small for full batch

typedef unsigned short u16;
typedef __attribute__((ext_vector_type(8))) short bf16x8;
typedef __attribute__((ext_vector_type(8))) unsigned short u16x8;
typedef __attribute__((ext_vector_type(4))) float f32x4;
typedef __attribute__((ext_vector_type(8))) float f32x8;

__device__ __forceinline__ float softplusf(float x) {
    return fmaxf(x, 0.0f) + log1pf(__expf(-fabsf(x)));
}
// fast softplus for spline path (tolerance is bf16-scale)
__device__ __forceinline__ float softplus_fast(float x) {
    return fmaxf(x, 0.0f) + __logf(1.0f + __expf(-fabsf(x)));
}
__device__ __forceinline__ float frcp(float x) { return __builtin_amdgcn_rcpf(x); }
__device__ __forceinline__ u16 f2bf(float f) {
    __hip_bfloat16 h = __float2bfloat16(f);
    return *reinterpret_cast<u16*>(&h);
}
__device__ __forceinline__ float bf2f(u16 u) {
    return __uint_as_float(((unsigned int)u) << 16);
}

// global->LDS direct 16B load; LDS dest is wave-uniform base + lane*16.
__device__ __forceinline__ void gload16(const u16* g, const u16* s) {
    __builtin_amdgcn_global_load_lds(
        (const __attribute__((address_space(1))) unsigned int*)(unsigned long long)(uintptr_t)g,
        (__attribute__((address_space(3))) unsigned int*)(unsigned int)(uintptr_t)s,
        16, 0, 0);
}

// bijective XCD-chunked swizzle (m204): contiguous grid chunk per XCD
__device__ __forceinline__ int xcd_swz(int bid, int nwg) {
    int q = nwg >> 3, r = nwg & 7;
    int xcd = bid & 7, idx = bid >> 3;
    return (xcd < r ? xcd * (q + 1) : r * (q + 1) + (xcd - r) * q) + idx;
}

// ---------------- prep: context -> bf16 --------------------------------------
__global__ void cvt_ctx(const float* __restrict__ c, u16* __restrict__ o) {
    int i = blockIdx.x * 256 + threadIdx.x;
    if (i < BATCH * CDIM) o[i] = f2bf(c[i]);
}

// ---------------- prep: W1t/W2t transposed bf16 ------------------------------
__global__ void prep_w12(const float* __restrict__ W1, const float* __restrict__ W2,
                         u16* __restrict__ W1t, u16* __restrict__ W2t) {
    int i = blockIdx.x * 256 + threadIdx.x;
    if (i < NL * HID * CDIM) {   // W1t[l][n][k] = W1[l][k][n]
        int k = i % CDIM; int n = (i / CDIM) % HID; int l = i / (CDIM * HID);
        W1t[i] = f2bf(W1[(l * CDIM + k) * HID + n]);
    }
    if (i < NL * HID * HID) {    // W2t[l][n][k] = W2[l][k][n]
        int k = i % HID; int n = (i / HID) % HID; int l = i / (HID * HID);
        W2t[i] = f2bf(W2[(l * HID + k) * HID + n]);
    }
}

// ---------------- prep: W3t padded/transposed + padded bias ------------------
__global__ void prep_w3(const float* __restrict__ W3, const float* __restrict__ b3,
                        u16* __restrict__ W3t, float* __restrict__ b3p) {
    int i = blockIdx.x * 256 + threadIdx.x;
    if (i < NL * NPAD * HID) {   // W3t[l][n][k], n = d*24+p
        int k = i % HID; int n = (i / HID) % NPAD; int l = i / (HID * NPAD);
        int dd = n / PPDP, p = n % PPDP;
        W3t[i] = (p < PPD) ? f2bf(W3[(l * HID + k) * ODIM + dd * PPD + p]) : (u16)0;
    }
    if (i < NL * NPAD) {
        int n = i % NPAD; int l = i / NPAD;
        int dd = n / PPDP, p = n % PPDP;
        b3p[i] = (p < PPD) ? b3[l * ODIM + dd * PPD + p] : 0.0f;
    }
}

// ---------------- precompute: A_t = (L@U)^T per layer, total LU logdet -------
__global__ void lu_prep(const float* __restrict__ lower_e,
                        const float* __restrict__ upper_e,
                        const float* __restrict__ udiag,
                        float* __restrict__ At, float* __restrict__ lu_const) {
    int l = blockIdx.x;
    int t = threadIdx.x;
    __shared__ float Ls[D * D];
    __shared__ float Us[D * D];
    __shared__ float red[4];
    for (int idx = t; idx < D * D; idx += 256) {
        int i = idx >> 6, j = idx & 63;
        float lv;
        if (i == j)      lv = 1.0f;
        else if (i > j)  lv = lower_e[l * NTRI + (i * (i - 1)) / 2 + j];
        else             lv = 0.0f;
        Ls[idx] = lv;
        float uv;
        if (i == j)      uv = softplusf(udiag[l * D + i]) + 0.001f;
        else if (j > i)  uv = upper_e[l * NTRI + i * (D - 1) - (i * (i - 1)) / 2 + (j - i - 1)];
        else             uv = 0.0f;
        Us[idx] = uv;
    }
    __syncthreads();
    for (int idx = t; idx < D * D; idx += 256) {
        int i = idx >> 6, j = idx & 63;
        float acc = 0.0f;
        int km = min(i, j);
        for (int k = 0; k <= km; ++k) acc += Ls[i * D + k] * Us[k * D + j];
        At[(l * D + j) * D + i] = acc;   // transposed store
    }
    // parallel log-sum reduction
    if (l == 0) {
        float s = 0.0f;
        for (int i = t; i < NL * D; i += 256)
            s += __logf(softplusf(udiag[i]) + 0.001f);
#pragma unroll
        for (int off = 32; off; off >>= 1) s += __shfl_xor(s, off);
        if ((t & 63) == 0) red[t >> 6] = s;
        __syncthreads();
        if (t == 0) lu_const[0] = red[0] + red[1] + red[2] + red[3];
    }
}

// ---------------- init: copy x, zero logdet ----------------------------------
__global__ void init_kernel(const float* __restrict__ inp, float* __restrict__ x,
                            float* __restrict__ logdet) {
    int i = blockIdx.x * 256 + threadIdx.x;
    if (i < BATCH * D) x[i] = inp[i];
    if (i < BATCH) logdet[i] = 0.0f;
}

// ---------------- MFMA GEMM: C = [relu](A @ Bt^T + bias), bf16 in/out --------
template<int RELU>
__global__ __launch_bounds__(256) void gemm_bf16(
    const u16* __restrict__ A, const u16* __restrict__ Bt,
    const float* __restrict__ bias, u16* __restrict__ Cv,
    int N, int K, int ncol)
{
    __shared__ u16 lds[16384];   // A: [0,8192) ushorts (16KB), B: [8192,16384)
    const int t = threadIdx.x;
    const int w = t >> 6, l = t & 63;
    const int wm = w >> 1, wn = w & 1;
    const int wg = xcd_swz(blockIdx.x, gridDim.x);
    const size_t m0 = (size_t)(wg / ncol) * 128;
    const int n0 = (wg % ncol) * 128;
    const int lrow = l & 15, lk = l >> 4;
    const int srow = l >> 3, sslot = l & 7;

    f32x4 acc[4][4] = {};

    for (int k0 = 0; k0 < K; k0 += 64) {
#pragma unroll
        for (int q = 0; q < 4; ++q) {
            int c = q * 4 + w;
            int row = c * 8 + srow;
            int slog = sslot ^ (row & 7);
            gload16(A + (m0 + row) * K + k0 + slog * 8, &lds[c * 512]);
        }
#pragma unroll
        for (int q = 0; q < 4; ++q) {
            int c = q * 4 + w;
            int row = c * 8 + srow;
            int slog = sslot ^ (row & 7);
            gload16(Bt + (size_t)(n0 + row) * K + k0 + slog * 8, &lds[8192 + c * 512]);
        }
        __syncthreads();
#pragma unroll
        for (int ks = 0; ks < 2; ++ks) {
            bf16x8 a[4], b[4];
#pragma unroll
            for (int mf = 0; mf < 4; ++mf) {
                int row = wm * 64 + mf * 16 + lrow;
                int slot = (ks * 4 + lk) ^ (row & 7);
                a[mf] = *(const bf16x8*)&lds[row * 64 + slot * 8];
            }
#pragma unroll
            for (int nf = 0; nf < 4; ++nf) {
                int row = wn * 64 + nf * 16 + lrow;
                int slot = (ks * 4 + lk) ^ (row & 7);
                b[nf] = *(const bf16x8*)&lds[8192 + row * 64 + slot * 8];
            }
#pragma unroll
            for (int mf = 0; mf < 4; ++mf)
#pragma unroll
                for (int nf = 0; nf < 4; ++nf)
                    acc[mf][nf] = __builtin_amdgcn_mfma_f32_16x16x32_bf16(
                        a[mf], b[nf], acc[mf][nf], 0, 0, 0);
        }
        __syncthreads();
    }
#pragma unroll
    for (int nf = 0; nf < 4; ++nf) {
        int col = n0 + wn * 64 + nf * 16 + lrow;
        float bv = bias[col];
#pragma unroll
        for (int mf = 0; mf < 4; ++mf) {
            size_t rbase = m0 + wm * 64 + mf * 16 + lk * 4;
#pragma unroll
            for (int i = 0; i < 4; ++i) {
                float v = acc[mf][nf][i] + bv;
                if (RELU) v = fmaxf(v, 0.0f);
                Cv[(rbase + i) * N + col] = f2bf(v);
            }
        }
    }
}

// ---------------- spline: softmax-cumsum of 8 logits -> boundaries 1..8 ------
// returns c where c[i] = boundary_{i+1} (boundary_0 = -5 const, c[7] = +5)
__device__ __forceinline__ f32x8 cumb(f32x8 p) {
    float m = fmaxf(fmaxf(fmaxf(p[0], p[1]), fmaxf(p[2], p[3])),
                    fmaxf(fmaxf(p[4], p[5]), fmaxf(p[6], p[7])));
    f32x8 e;
    float s = 0.0f;
#pragma unroll
    for (int i = 0; i < 8; ++i) { e[i] = __expf(p[i] - m); s += e[i]; }
    float tt = 0.992f * frcp(s);
    f32x8 c;
    float run = 0.0f;
#pragma unroll
    for (int i = 0; i < 7; ++i) {
        run = fmaf(tt, e[i], run + 0.001f);
        c[i] = fmaf(10.0f, run, -5.0f);
    }
    c[7] = 5.0f;
    return c;
}

// rational-quadratic spline, all state in ext-vectors (no address-taken arrays)
__device__ __forceinline__ void rqs_v(float xv, f32x8 uw, f32x8 uh, f32x8 ud,
                                      float& yo, float& ldo) {
    f32x8 cw = cumb(uw);
    f32x8 ch = cumb(uh);
    f32x8 dv;
#pragma unroll
    for (int i = 0; i < 7; ++i) dv[i] = 0.001f + softplus_fast(ud[i]);
    float xc = fminf(fmaxf(xv, -5.0f), 5.0f);
    float icw = -5.0f, icw1 = cw[0], ich = -5.0f, ich1 = ch[0];
    float d0 = 1.0f, d1 = dv[0];
#pragma unroll
    for (int k = 1; k < 8; ++k) {
        bool sel = (xc >= cw[k - 1]);
        icw  = sel ? cw[k - 1] : icw;
        icw1 = sel ? cw[k]     : icw1;
        ich  = sel ? ch[k - 1] : ich;
        ich1 = sel ? ch[k]     : ich1;
        d0   = sel ? dv[k - 1] : d0;
        d1   = sel ? ((k < 7) ? dv[k] : 1.0f) : d1;
    }
    float iw  = icw1 - icw;
    float ih  = ich1 - ich;
    float riw = frcp(iw);
    float dlt = ih * riw;
    float th  = (xc - icw) * riw;
    float omt = 1.0f - th;
    float tomt = th * omt;
    float numer = ih * (dlt * th * th + d0 * tomt);
    float den = dlt + (d0 + d1 - 2.0f * dlt) * tomt;
    float rden = frcp(den);
    float outv = ich + numer * rden;
    float dnum = dlt * dlt * (d1 * th * th + 2.0f * dlt * tomt + d0 * omt * omt);
    float ld = __logf(dnum * rden * rden);
    bool inside = (xv >= -5.0f) && (xv <= 5.0f);
    yo  = inside ? outv : xv;
    ldo = inside ? ld : 0.0f;
}

// ---------------- spline + LU: one row per wave, 8 rows/block ----------------
__global__ __launch_bounds__(512) void spline_lu_kernel(
    const u16* __restrict__ params,   // [chunk][NPAD] bf16, chunk-local
    const float* __restrict__ At, const float* __restrict__ lu_bias,
    float* __restrict__ x, float* __restrict__ logdet,
    int l, int row_base)
{
    __shared__ float y_s[8 * D];
    const int t = threadIdx.x;
    const int d = t & 63, g = t >> 6;
    const size_t crow = (size_t)blockIdx.x * 8 + g;
    const size_t grow = (size_t)row_base + crow;

    // load 24 params (3 aligned u16x8: d*24 u16 = d*48 B, 48 % 16 == 0)
    const u16x8* pp = (const u16x8*)(params + crow * NPAD + d * PPDP);
    u16x8 q0 = pp[0], q1 = pp[1], q2 = pp[2];
    f32x8 uw, uh, ud;
#pragma unroll
    for (int j = 0; j < 8; ++j) {
        uw[j] = bf2f(q0[j]);
        uh[j] = bf2f(q1[j]);
        ud[j] = bf2f(q2[j]);   // element 7 is pad (unused)
    }
    float xv = x[grow * D + d];
    float y, ld;
    rqs_v(xv, uw, uh, ud, y, ld);
    y_s[g * D + d] = y;
#pragma unroll
    for (int off = 32; off; off >>= 1) ld += __shfl_xor(ld, off);
    if (d == 0) logdet[grow] += ld;
    __syncthreads();

    // LU: x_new[row g][dim d] = sum_j y[g][j] * A[d][j] + bias[d]
    float acc = lu_bias[l * D + d];
    const float* ap = At + (size_t)l * D * D + d;   // At[(l*D+j)*D + d] = A[d][j]
#pragma unroll 8
    for (int j = 0; j < D; ++j)
        acc = fmaf(y_s[g * D + j], ap[j * D], acc);
    x[grow * D + d] = acc;
}

// ---------------- final: out = base + logdet ---------------------------------
__global__ void final_kernel(const float* __restrict__ x,
                             const float* __restrict__ logdet,
                             const float* __restrict__ lu_const,
                             float* __restrict__ out) {
    int t = threadIdx.x;
    int b = blockIdx.x * 4 + (t >> 6);
    int d = t & 63;
    float v = x[(size_t)b * D + d];
    float s = v * v;
#pragma unroll
    for (int off = 32; off; off >>= 1) s += __shfl_xor(s, off);
    if (d == 0)
        out[b] = logdet[b] + lu_const[0] - 0.5f * s - 0.5f * 64.0f * 1.8378770664093453f;
}

extern "C" void kernel_launch(void* const* d_in, const int* in_sizes, int n_in,
                              void* d_out, int out_size, void* d_ws, size_t ws_size,
                              hipStream_t stream) {
    const float* inputs  = (const float*)d_in[0];
    const float* context = (const float*)d_in[1];
    const float* W1      = (const float*)d_in[2];
    const float* b1      = (const float*)d_in[3];
    const float* W2      = (const float*)d_in[4];
    const float* b2      = (const float*)d_in[5];
    const float* W3      = (const float*)d_in[6];
    const float* b3      = (const float*)d_in[7];
    const float* lu_bias = (const float*)d_in[8];
    const float* lower_e = (const float*)d_in[9];
    const float* upper_e = (const float*)d_in[10];
    const float* udiag   = (const float*)d_in[11];
    float* out = (float*)d_out;

    char* p = (char*)d_ws;
    auto alloc = [&](size_t bytes) { void* r = p; p += (bytes + 255) & ~(size_t)255; return r; };
    float* x        = (float*)alloc((size_t)BATCH * D * 4);
    float* logdet   = (float*)alloc((size_t)BATCH * 4);
    float* At       = (float*)alloc((size_t)NL * D * D * 4);
    float* lu_const = (float*)alloc(256);
    u16*   ctx_bf   = (u16*)alloc((size_t)BATCH * CDIM * 2);
    u16*   hh1      = (u16*)alloc((size_t)BATCH * HID * 2);
    u16*   hh2      = (u16*)alloc((size_t)BATCH * HID * 2);
    u16*   W1t      = (u16*)alloc((size_t)NL * HID * CDIM * 2);
    u16*   W2t      = (u16*)alloc((size_t)NL * HID * HID * 2);
    u16*   W3t      = (u16*)alloc((size_t)NL * NPAD * HID * 2);
    float* b3p      = (float*)alloc((size_t)NL * NPAD * 4);

    size_t used = (size_t)(p - (char*)d_ws);
    int chunk = (ws_size - used >= (size_t)BATCH * NPAD * 2 + 256) ? BATCH : CHUNK;
    u16* paramsB = (u16*)alloc((size_t)chunk * NPAD * 2);

    cvt_ctx<<<(BATCH * CDIM + 255) / 256, 256, 0, stream>>>(context, ctx_bf);
    prep_w12<<<(NL * HID * HID + 255) / 256, 256, 0, stream>>>(W1, W2, W1t, W2t);
    prep_w3<<<(NL * NPAD * HID + 255) / 256, 256, 0, stream>>>(W3, b3, W3t, b3p);
    lu_prep<<<NL, 256, 0, stream>>>(lower_e, upper_e, udiag, At, lu_const);
    init_kernel<<<(BATCH * D + 255) / 256, 256, 0, stream>>>(inputs, x, logdet);

    for (int l = 0; l < NL; ++l) {
        gemm_bf16<1><<<(BATCH / 128) * 2, 256, 0, stream>>>(
            ctx_bf, W1t + (size_t)l * HID * CDIM, b1 + l * HID, hh1, HID, CDIM, 2);
        gemm_bf16<1><<<(BATCH / 128) * 2, 256, 0, stream>>>(
            hh1, W2t + (size_t)l * HID * HID, b2 + l * HID, hh2, HID, HID, 2);
        for (int c = 0; c < BATCH / chunk; ++c) {
            gemm_bf16<0><<<(chunk / 128) * (NPAD / 128), 256, 0, stream>>>(
                hh2 + (size_t)c * chunk * HID, W3t + (size_t)l * NPAD * HID,
                b3p + l * NPAD, paramsB, NPAD, HID, NPAD / 128);
            spline_lu_kernel<<<chunk / 8, 512, 0, stream>>>(
                paramsB, At, lu_bias, x, logdet, l, c * chunk);
        }
    }
    final_kernel<<<BATCH / 4, 256, 0, stream>>>(x, logdet, lu_const, out);
}